// Round 2
// baseline (256.484 us; speedup 1.0000x reference)
//
#include <hip/hip_runtime.h>
#include <cstdint>

// B=16384, D=512, U=512, K=D+U=1024, N=4U=2048
#define HU 8388608  // 16384*512, offset of c-part in out

typedef __attribute__((ext_vector_type(8))) short short8_t;
typedef __attribute__((ext_vector_type(4))) float float4_t;
typedef __attribute__((ext_vector_type(4))) unsigned int uint4_t;
typedef __attribute__((ext_vector_type(2))) unsigned int uint2_t;

__device__ __forceinline__ unsigned short f2bf(float x) {
    unsigned u = __builtin_bit_cast(unsigned, x);
    u += 0x7fffu + ((u >> 16) & 1u);  // RNE
    return (unsigned short)(u >> 16);
}

__device__ __forceinline__ void gll16(const void* g, const void* lds) {
    __builtin_amdgcn_global_load_lds(
        (const __attribute__((address_space(1))) unsigned int*)(uintptr_t)g,
        (__attribute__((address_space(3))) unsigned int*)(unsigned int)(uintptr_t)lds,
        16, 0, 0);
}

__device__ __forceinline__ float sigm(float x) {
    return __builtin_amdgcn_rcpf(1.f + __expf(-x));
}
__device__ __forceinline__ float tanhfast(float x) {
    float ax = fabsf(x);
    float e = __expf(-2.f * ax);
    float r = (1.f - e) * __builtin_amdgcn_rcpf(1.f + e);
    return copysignf(r, x);
}

// ---------- merged pre-pass: blocks [0,8192) concat+cvt, [8192,10240) transpose ----------
__global__ __launch_bounds__(256) void prep(const float* __restrict__ x,
                                            const float* __restrict__ h,
                                            const float* __restrict__ W,
                                            const float* __restrict__ R,
                                            unsigned short* __restrict__ xh,
                                            unsigned short* __restrict__ btw) {
    __shared__ float t[32 * 33];
    int bid = blockIdx.x;
    int tid = threadIdx.x;
    if (bid < 8192) {
        // xh[b][k] = bf16(k<512 ? x[b][k] : h[b][k-512])
        int n = bid * 256 + tid;
        int e8 = n * 8;
        int row = e8 >> 10, col = e8 & 1023;
        const float* src = (col < 512) ? (x + row * 512 + col) : (h + row * 512 + (col - 512));
        float4_t lo = *(const float4_t*)src;
        float4_t hi = *(const float4_t*)(src + 4);
        uint4_t o;
        o.x = (unsigned)f2bf(lo.x) | ((unsigned)f2bf(lo.y) << 16);
        o.y = (unsigned)f2bf(lo.z) | ((unsigned)f2bf(lo.w) << 16);
        o.z = (unsigned)f2bf(hi.x) | ((unsigned)f2bf(hi.y) << 16);
        o.w = (unsigned)f2bf(hi.z) | ((unsigned)f2bf(hi.w) << 16);
        *(uint4_t*)(xh + e8) = o;
    } else {
        // Btw[n'][k] = bf16(Wall[k][n]), n' = ub*128 + uo*4 + g
        int gid = bid - 8192;
        int kt = gid & 31, ub = (gid >> 5) & 15, g = gid >> 9;
        int ky = tid >> 3, ux4 = (tid & 7) * 4;
        int kg = kt * 32 + ky;
        int col = g * 512 + ub * 32 + ux4;
        const float* src = (kg < 512) ? (W + (size_t)kg * 2048 + col)
                                      : (R + (size_t)(kg - 512) * 2048 + col);
        float4_t v = *(const float4_t*)src;
        t[ky * 33 + ux4 + 0] = v.x;
        t[ky * 33 + ux4 + 1] = v.y;
        t[ky * 33 + ux4 + 2] = v.z;
        t[ky * 33 + ux4 + 3] = v.w;
        __syncthreads();
        int uo = tid >> 3, kx4 = (tid & 7) * 4;
        unsigned short o0 = f2bf(t[(kx4 + 0) * 33 + uo]);
        unsigned short o1 = f2bf(t[(kx4 + 1) * 33 + uo]);
        unsigned short o2 = f2bf(t[(kx4 + 2) * 33 + uo]);
        unsigned short o3 = f2bf(t[(kx4 + 3) * 33 + uo]);
        uint2_t p;
        p.x = (unsigned)o0 | ((unsigned)o1 << 16);
        p.y = (unsigned)o2 | ((unsigned)o3 << 16);
        *(uint2_t*)(btw + (size_t)(ub * 128 + uo * 4 + g) * 1024 + kt * 32 + kx4) = p;
    }
}

// ---------- main: 128x128 tile GEMM (K=1024) + fused LSTM epilogue ----------
// LDS: As/Bs (16.4 KB) unioned with zs (33.8 KB) -> ~35 KB total -> 4 blocks/CU (VGPR-capped)
__global__ __launch_bounds__(256, 4) void lstm_main(
    const unsigned short* __restrict__ xh,   // [16384][1024] bf16
    const unsigned short* __restrict__ btw,  // [2048][1024] bf16, gate-interleaved rows
    const float* __restrict__ c_tm1,         // [16384][512]
    const float* __restrict__ pw,            // [512][3]
    const float* __restrict__ bias,          // [2048]
    float* __restrict__ out)                 // [2][16384][512]
{
    __shared__ float smem[64 * 132];         // zs overlays As+Bs (both dead post K-loop)
    __shared__ float4_t bias4s[32];
    __shared__ float pwis[32], pwfs[32], pwos[32];

    short* As = (short*)smem;                // 128*32 shorts = 8 KB
    short* Bs = As + 128 * 32;               // 128*32 shorts = 8 KB
    float* zs = smem;                        // 64*132 floats = 33.8 KB

    int tid = threadIdx.x;
    int w = tid >> 6, lane = tid & 63;
    int bid = blockIdx.x;
    int nb = bid & 15, mb = bid >> 4;
    int u0 = nb * 32;

    if (tid < 32) {
        int u = u0 + tid;
        float4_t b4;
        b4.x = bias[u]; b4.y = bias[512 + u]; b4.z = bias[1024 + u]; b4.w = bias[1536 + u];
        bias4s[tid] = b4;
        pwis[tid] = pw[u * 3 + 0];
        pwfs[tid] = pw[u * 3 + 1];
        pwos[tid] = pw[u * 3 + 2];
    }

    float4_t acc[4][4];
#pragma unroll
    for (int i = 0; i < 4; i++)
#pragma unroll
        for (int j = 0; j < 4; j++) acc[i][j] = (float4_t){0.f, 0.f, 0.f, 0.f};

    int m = lane & 15, q = lane >> 4;
    int wrow = w & 1, wcol = w >> 1;

    // XOR-swizzled staging: lane l loads global chunk (l&3)^((l>>3)&3), writes LDS slot l&3.
    // Reader recovers global chunk q of row m from slot q^((m>>1)&3). Kills 8-way conflicts.
    int swz = ((lane & 3) ^ ((lane >> 3) & 3)) * 8;
    const unsigned short* aG = xh + (size_t)(mb * 128 + w * 32 + (lane >> 2)) * 1024 + swz;
    const unsigned short* bG = btw + (size_t)(nb * 128 + w * 32 + (lane >> 2)) * 1024 + swz;
    short* aS0 = &As[(w * 32) * 32];
    short* aS1 = &As[(w * 32 + 16) * 32];
    short* bS0 = &Bs[(w * 32) * 32];
    short* bS1 = &Bs[(w * 32 + 16) * 32];

    for (int kt = 0; kt < 32; ++kt) {
        int ko = kt * 32;
        gll16(aG + ko, aS0);
        gll16(aG + ko + 16 * 1024, aS1);
        gll16(bG + ko, bS0);
        gll16(bG + ko + 16 * 1024, bS1);
        __syncthreads();
        int slot = (q ^ ((m >> 1) & 3)) * 8;
        short8_t a[4], b[4];
#pragma unroll
        for (int i = 0; i < 4; i++)
            a[i] = *(const short8_t*)&As[(wrow * 64 + i * 16 + m) * 32 + slot];
#pragma unroll
        for (int j = 0; j < 4; j++)
            b[j] = *(const short8_t*)&Bs[(wcol * 64 + j * 16 + m) * 32 + slot];
#pragma unroll
        for (int i = 0; i < 4; i++)
#pragma unroll
            for (int j = 0; j < 4; j++)
                acc[i][j] = __builtin_amdgcn_mfma_f32_16x16x32_bf16(a[i], b[j], acc[i][j], 0, 0, 0);
        __syncthreads();
    }

    // ---- fused epilogue, two 64-row halves (zs aliases As/Bs; K-loop ended with barrier) ----
#pragma unroll
    for (int hh = 0; hh < 2; ++hh) {
        if (wrow == hh) {
#pragma unroll
            for (int i = 0; i < 4; i++)
#pragma unroll
                for (int j = 0; j < 4; j++) {
                    int c = wcol * 64 + j * 16 + m;
                    int rbase = i * 16 + q * 4;
#pragma unroll
                    for (int r = 0; r < 4; r++)
                        zs[(rbase + r) * 132 + c] = acc[i][j][r];
                }
        }
        __syncthreads();
#pragma unroll
        for (int it = 0; it < 2; ++it) {
            int r = (tid >> 3) + it * 32;            // row within half [0,64)
            int uo4 = (tid & 7) * 4;                 // 4 consecutive u per thread
            int grow = mb * 128 + hh * 64 + r;       // global batch row
            float4_t c14 = *(const float4_t*)&c_tm1[(size_t)grow * 512 + u0 + uo4];
            float4_t pwi4 = *(const float4_t*)&pwis[uo4];
            float4_t pwf4 = *(const float4_t*)&pwfs[uo4];
            float4_t pwo4 = *(const float4_t*)&pwos[uo4];
            float4_t hv, cv;
#pragma unroll
            for (int u = 0; u < 4; ++u) {
                float4_t z4 = *(const float4_t*)&zs[r * 132 + (uo4 + u) * 4];  // (i,f,g,o)
                float4_t b4 = bias4s[uo4 + u];
                float c1 = c14[u];
                float iv = sigm(z4.x + b4.x + c1 * pwi4[u]);
                float fv = sigm(z4.y + b4.y + c1 * pwf4[u]);
                float gv = tanhfast(z4.z + b4.z);
                float cc = fv * c1 + iv * gv;
                float ov = sigm(z4.w + b4.w + cc * pwo4[u]);
                hv[u] = ov * tanhfast(cc);
                cv[u] = cc;
            }
            *(float4_t*)&out[(size_t)grow * 512 + u0 + uo4] = hv;
            *(float4_t*)&out[HU + (size_t)grow * 512 + u0 + uo4] = cv;
        }
        __syncthreads();
    }
}

extern "C" void kernel_launch(void* const* d_in, const int* in_sizes, int n_in,
                              void* d_out, int out_size, void* d_ws, size_t ws_size,
                              hipStream_t stream) {
    const float* x    = (const float*)d_in[0];
    const float* h    = (const float*)d_in[1];
    const float* c    = (const float*)d_in[2];
    const float* W    = (const float*)d_in[3];
    const float* R    = (const float*)d_in[4];
    const float* pw   = (const float*)d_in[5];
    const float* bias = (const float*)d_in[6];
    float* out = (float*)d_out;

    unsigned short* xh  = (unsigned short*)d_ws;                        // 33,554,432 B
    unsigned short* btw = (unsigned short*)((char*)d_ws + 33554432u);   // + 4,194,304 B

    prep<<<10240, 256, 0, stream>>>(x, h, W, R, xh, btw);
    lstm_main<<<2048, 256, 0, stream>>>(xh, btw, c, pw, bias, out);
}

// Round 3
// 238.326 us; speedup vs baseline: 1.0762x; 1.0762x over previous
//
#include <hip/hip_runtime.h>
#include <cstdint>

// B=16384, D=512, U=512, K=D+U=1024, N=4U=2048
#define HU 8388608  // 16384*512, offset of c-part in out

typedef __attribute__((ext_vector_type(8))) short short8_t;
typedef __attribute__((ext_vector_type(4))) float float4_t;
typedef __attribute__((ext_vector_type(16))) float float16_t;
typedef __attribute__((ext_vector_type(4))) unsigned int uint4_t;
typedef __attribute__((ext_vector_type(2))) unsigned int uint2_t;

__device__ __forceinline__ unsigned short f2bf(float x) {
    unsigned u = __builtin_bit_cast(unsigned, x);
    u += 0x7fffu + ((u >> 16) & 1u);  // RNE
    return (unsigned short)(u >> 16);
}

__device__ __forceinline__ void gll16(const void* g, const void* lds) {
    __builtin_amdgcn_global_load_lds(
        (const __attribute__((address_space(1))) unsigned int*)(uintptr_t)g,
        (__attribute__((address_space(3))) unsigned int*)(unsigned int)(uintptr_t)lds,
        16, 0, 0);
}

__device__ __forceinline__ float sigm(float x) {
    return __builtin_amdgcn_rcpf(1.f + __expf(-x));
}
__device__ __forceinline__ float tanhfast(float x) {
    float ax = fabsf(x);
    float e = __expf(-2.f * ax);
    float r = (1.f - e) * __builtin_amdgcn_rcpf(1.f + e);
    return copysignf(r, x);
}

// ---------- merged pre-pass: blocks [0,8192) concat+cvt, [8192,10240) transpose ----------
__global__ __launch_bounds__(256) void prep(const float* __restrict__ x,
                                            const float* __restrict__ h,
                                            const float* __restrict__ W,
                                            const float* __restrict__ R,
                                            unsigned short* __restrict__ xh,
                                            unsigned short* __restrict__ btw) {
    __shared__ float t[32 * 33];
    int bid = blockIdx.x;
    int tid = threadIdx.x;
    if (bid < 8192) {
        int n = bid * 256 + tid;
        int e8 = n * 8;
        int row = e8 >> 10, col = e8 & 1023;
        const float* src = (col < 512) ? (x + row * 512 + col) : (h + row * 512 + (col - 512));
        float4_t lo = *(const float4_t*)src;
        float4_t hi = *(const float4_t*)(src + 4);
        uint4_t o;
        o.x = (unsigned)f2bf(lo.x) | ((unsigned)f2bf(lo.y) << 16);
        o.y = (unsigned)f2bf(lo.z) | ((unsigned)f2bf(lo.w) << 16);
        o.z = (unsigned)f2bf(hi.x) | ((unsigned)f2bf(hi.y) << 16);
        o.w = (unsigned)f2bf(hi.z) | ((unsigned)f2bf(hi.w) << 16);
        *(uint4_t*)(xh + e8) = o;
    } else {
        // Btw[n'][k] = bf16(Wall[k][n]), n' = ub*128 + uo*4 + g
        int gid = bid - 8192;
        int kt = gid & 31, ub = (gid >> 5) & 15, g = gid >> 9;
        int ky = tid >> 3, ux4 = (tid & 7) * 4;
        int kg = kt * 32 + ky;
        int col = g * 512 + ub * 32 + ux4;
        const float* src = (kg < 512) ? (W + (size_t)kg * 2048 + col)
                                      : (R + (size_t)(kg - 512) * 2048 + col);
        float4_t v = *(const float4_t*)src;
        t[ky * 33 + ux4 + 0] = v.x;
        t[ky * 33 + ux4 + 1] = v.y;
        t[ky * 33 + ux4 + 2] = v.z;
        t[ky * 33 + ux4 + 3] = v.w;
        __syncthreads();
        int uo = tid >> 3, kx4 = (tid & 7) * 4;
        unsigned short o0 = f2bf(t[(kx4 + 0) * 33 + uo]);
        unsigned short o1 = f2bf(t[(kx4 + 1) * 33 + uo]);
        unsigned short o2 = f2bf(t[(kx4 + 2) * 33 + uo]);
        unsigned short o3 = f2bf(t[(kx4 + 3) * 33 + uo]);
        uint2_t p;
        p.x = (unsigned)o0 | ((unsigned)o1 << 16);
        p.y = (unsigned)o2 | ((unsigned)o3 << 16);
        *(uint2_t*)(btw + (size_t)(ub * 128 + uo * 4 + g) * 1024 + kt * 32 + kx4) = p;
    }
}

// ---------- main: 128x128 tile GEMM, BK=64, 32x32x16 MFMA, fused LSTM epilogue ----------
// LDS: As+Bs (32 KB, BK=64) unioned with zs (33.8 KB) -> ~34.7 KB; 3 waves/EU reg budget.
__global__ __launch_bounds__(256, 3) void lstm_main(
    const unsigned short* __restrict__ xh,   // [16384][1024] bf16
    const unsigned short* __restrict__ btw,  // [2048][1024] bf16, gate-interleaved rows
    const float* __restrict__ c_tm1,         // [16384][512]
    const float* __restrict__ pw,            // [512][3]
    const float* __restrict__ bias,          // [2048]
    float* __restrict__ out)                 // [2][16384][512]
{
    __shared__ float4_t smem4[8448 / 4];     // 33792 B: zs(64x132 f32) overlays As+Bs
    __shared__ float4_t bias4s[32];
    __shared__ float pwis[32], pwfs[32], pwos[32];

    float* zs = (float*)smem4;
    short* As = (short*)smem4;               // 128 rows x 64 k = 16384 B
    short* Bs = As + 128 * 64;               // 16384 B

    int tid = threadIdx.x;
    int w = tid >> 6, lane = tid & 63;
    int bid = blockIdx.x;
    int nb = bid & 15, mb = bid >> 4;
    int u0 = nb * 32;

    if (tid < 32) {
        int u = u0 + tid;
        float4_t b4;
        b4.x = bias[u]; b4.y = bias[512 + u]; b4.z = bias[1024 + u]; b4.w = bias[1536 + u];
        bias4s[tid] = b4;
        pwis[tid] = pw[u * 3 + 0];
        pwfs[tid] = pw[u * 3 + 1];
        pwos[tid] = pw[u * 3 + 2];
    }

    float16_t acc[2][2];
#pragma unroll
    for (int i = 0; i < 2; i++)
#pragma unroll
        for (int j = 0; j < 2; j++)
#pragma unroll
            for (int r = 0; r < 16; r++) acc[i][j][r] = 0.f;

    int m5 = lane & 31, hfl = lane >> 5;     // MFMA A/B: row=lane&31, k=(lane>>5)*8+i
    int wrow = w & 1, wcol = w >> 1;

    // Staging: rows of 128 B (8 chunks of 16 B). LDS(row r, slot t) holds global chunk t^(r&7).
    // gll16 lane l -> row base+ (l>>3), slot l&7 -> fetch global chunk (l&7)^((l>>3)&7).
    int lr = lane >> 3;                       // 0..7
    int gch = (lane & 7) ^ lr;                // swizzled global chunk
    const unsigned short* aG = xh + (size_t)(mb * 128 + w * 32 + lr) * 1024 + gch * 8;
    const unsigned short* bG = btw + (size_t)(nb * 128 + w * 32 + lr) * 1024 + gch * 8;
    short* aS = As + (w * 32) * 64;           // wave stages rows [w*32, w*32+32)
    short* bS = Bs + (w * 32) * 64;

    int sw = (m5 & 7) * 8;                    // reader swizzle (in shorts)

    for (int kt = 0; kt < 16; ++kt) {
        int ko = kt * 64;
#pragma unroll
        for (int s = 0; s < 4; ++s) {
            gll16(aG + ko + s * 8 * 1024, aS + s * 512);
            gll16(bG + ko + s * 8 * 1024, bS + s * 512);
        }
        __syncthreads();
#pragma unroll
        for (int s = 0; s < 4; ++s) {
            int c = (s * 2 + hfl) * 8;        // wanted chunk (shorts)
            int t = c ^ sw;                   // swizzled slot (shorts)
            short8_t a0 = *(const short8_t*)&As[(wrow * 64 + m5) * 64 + t];
            short8_t a1 = *(const short8_t*)&As[(wrow * 64 + 32 + m5) * 64 + t];
            short8_t b0 = *(const short8_t*)&Bs[(wcol * 64 + m5) * 64 + t];
            short8_t b1 = *(const short8_t*)&Bs[(wcol * 64 + 32 + m5) * 64 + t];
            acc[0][0] = __builtin_amdgcn_mfma_f32_32x32x16_bf16(a0, b0, acc[0][0], 0, 0, 0);
            acc[0][1] = __builtin_amdgcn_mfma_f32_32x32x16_bf16(a0, b1, acc[0][1], 0, 0, 0);
            acc[1][0] = __builtin_amdgcn_mfma_f32_32x32x16_bf16(a1, b0, acc[1][0], 0, 0, 0);
            acc[1][1] = __builtin_amdgcn_mfma_f32_32x32x16_bf16(a1, b1, acc[1][1], 0, 0, 0);
        }
        __syncthreads();
    }

    // ---- fused epilogue, two 64-row halves (zs aliases As/Bs) ----
    // 32x32 C/D: col=lane&31, row=(reg&3)+8*(reg>>2)+4*(lane>>5)
#pragma unroll
    for (int hh = 0; hh < 2; ++hh) {
        if (wrow == hh) {
#pragma unroll
            for (int i = 0; i < 2; i++)
#pragma unroll
                for (int j = 0; j < 2; j++) {
                    int cc = wcol * 64 + j * 32 + m5;
#pragma unroll
                    for (int reg = 0; reg < 16; reg++) {
                        int rr = (reg & 3) + 8 * (reg >> 2) + 4 * hfl;
                        zs[(i * 32 + rr) * 132 + cc] = acc[i][j][reg];
                    }
                }
        }
        __syncthreads();
#pragma unroll
        for (int it = 0; it < 2; ++it) {
            int r = (tid >> 3) + it * 32;            // row within half [0,64)
            int uo4 = (tid & 7) * 4;                 // 4 consecutive u per thread
            int grow = mb * 128 + hh * 64 + r;       // global batch row
            float4_t c14 = *(const float4_t*)&c_tm1[(size_t)grow * 512 + u0 + uo4];
            float4_t pwi4 = *(const float4_t*)&pwis[uo4];
            float4_t pwf4 = *(const float4_t*)&pwfs[uo4];
            float4_t pwo4 = *(const float4_t*)&pwos[uo4];
            float4_t hv, cv;
#pragma unroll
            for (int u = 0; u < 4; ++u) {
                float4_t z4 = *(const float4_t*)&zs[r * 132 + (uo4 + u) * 4];  // (i,f,g,o)
                float4_t b4 = bias4s[uo4 + u];
                float c1 = c14[u];
                float iv = sigm(z4.x + b4.x + c1 * pwi4[u]);
                float fv = sigm(z4.y + b4.y + c1 * pwf4[u]);
                float gv = tanhfast(z4.z + b4.z);
                float cc = fv * c1 + iv * gv;
                float ov = sigm(z4.w + b4.w + cc * pwo4[u]);
                hv[u] = ov * tanhfast(cc);
                cv[u] = cc;
            }
            *(float4_t*)&out[(size_t)grow * 512 + u0 + uo4] = hv;
            *(float4_t*)&out[HU + (size_t)grow * 512 + u0 + uo4] = cv;
        }
        __syncthreads();
    }
}

extern "C" void kernel_launch(void* const* d_in, const int* in_sizes, int n_in,
                              void* d_out, int out_size, void* d_ws, size_t ws_size,
                              hipStream_t stream) {
    const float* x    = (const float*)d_in[0];
    const float* h    = (const float*)d_in[1];
    const float* c    = (const float*)d_in[2];
    const float* W    = (const float*)d_in[3];
    const float* R    = (const float*)d_in[4];
    const float* pw   = (const float*)d_in[5];
    const float* bias = (const float*)d_in[6];
    float* out = (float*)d_out;

    unsigned short* xh  = (unsigned short*)d_ws;                        // 33,554,432 B
    unsigned short* btw = (unsigned short*)((char*)d_ws + 33554432u);   // + 4,194,304 B

    prep<<<10240, 256, 0, stream>>>(x, h, W, R, xh, btw);
    lstm_main<<<2048, 256, 0, stream>>>(xh, btw, c, pw, bias, out);
}